// Round 2
// baseline (1603.646 us; speedup 1.0000x reference)
//
#include <hip/hip_runtime.h>
#include <hip/hip_bf16.h>

// Problem constants (WholeBrainRateModel)
constexpr int kN   = 50000;    // nodes
constexpr int kH   = 64;       // hidden
constexpr int kB   = 2;        // batch
constexpr int kE   = 1000000;  // edges
constexpr int kObs = 128;
constexpr int kA   = 18;
constexpr int kAff = 512;
constexpr int kEff = 256;
constexpr int kNH  = kN * kH;
constexpr int kOutOff = 2 * kB * kA;  // 72 elements: mean+log_std before next_state
constexpr int kScanChunk  = 1024;
constexpr int kScanBlocks = (kN + kScanChunk - 1) / kScanChunk;  // 49

// dtype-adaptive load/store: flag==1 -> buffers are float32, else bf16
__device__ __forceinline__ float ldf(const void* p, int i, int f32) {
  if (f32) return ((const float*)p)[i];
  unsigned short u = ((const unsigned short*)p)[i];
  union { unsigned int x; float f; } v; v.x = ((unsigned int)u) << 16; return v.f;
}
__device__ __forceinline__ void stf(void* p, int i, float val, int f32) {
  if (f32) ((float*)p)[i] = val;
  else ((__hip_bfloat16*)p)[i] = __float2bfloat16(val);
}

// --- dtype detector: sample even u16s of a random-normal weight buffer ------
extern "C" __global__ void k_detect(const unsigned short* __restrict__ w,
                                    int* __restrict__ flag) {
  int t = threadIdx.x;  // 64 threads
  int hits = 0;
  for (int k = 0; k < 4; ++k) {
    unsigned short u = w[(t * 4 + k) * 2];  // even indices 0..510
    int e = (u >> 7) & 0xFF;
    if ((u & 0x7FFFu) != 0 && e >= 108 && e <= 128) hits++;
  }
  for (int off = 32; off; off >>= 1) hits += __shfl_down(hits, off);
  if (t == 0) flag[0] = (hits < 128) ? 1 : 0;  // few plausible-bf16 => f32
}

// --- prep: afferent flags + projected = obs @ W_in + b_in -------------------
extern "C" __global__ void k_prep(const void* __restrict__ obs,
                                  const void* __restrict__ W_in,
                                  const void* __restrict__ b_in,
                                  const int* __restrict__ aff_idx,
                                  const int* __restrict__ flag,
                                  int* __restrict__ flags,
                                  float* __restrict__ projected) {
  int f32 = flag[0];
  int t = threadIdx.x;
  if (t < kAff) flags[aff_idx[t]] = 1;
  if (t < kB * kH) {
    int b = t >> 6, h = t & 63;
    float acc = ldf(b_in, h, f32);
    for (int o = 0; o < kObs; ++o)
      acc += ldf(obs, b * kObs + o, f32) * ldf(W_in, o * kH + h, f32);
    projected[t] = acc;
  }
}

// --- CSR build: histogram, scan, scatter ------------------------------------
extern "C" __global__ void k_hist(const int* __restrict__ dst, int* __restrict__ deg) {
  int e = blockIdx.x * 256 + threadIdx.x;
  if (e < kE) {
    int d = dst[e];
    if ((unsigned)d < (unsigned)kN) atomicAdd(&deg[d], 1);
  }
}

extern "C" __global__ void k_scan1(const int* __restrict__ deg,
                                   int* __restrict__ row_off,
                                   int* __restrict__ partials) {
  __shared__ int sd[256];
  int t = threadIdx.x;
  int base = blockIdx.x * kScanChunk + t * 4;
  int d0 = (base + 0 < kN) ? deg[base + 0] : 0;
  int d1 = (base + 1 < kN) ? deg[base + 1] : 0;
  int d2 = (base + 2 < kN) ? deg[base + 2] : 0;
  int d3 = (base + 3 < kN) ? deg[base + 3] : 0;
  int s4 = d0 + d1 + d2 + d3;
  sd[t] = s4;
  __syncthreads();
  for (int off = 1; off < 256; off <<= 1) {
    int v = (t >= off) ? sd[t - off] : 0;
    __syncthreads();
    sd[t] += v;
    __syncthreads();
  }
  int excl = sd[t] - s4;
  if (t == 255) partials[blockIdx.x] = sd[255];
  if (base + 0 < kN) row_off[base + 0] = excl;
  excl += d0;
  if (base + 1 < kN) row_off[base + 1] = excl;
  excl += d1;
  if (base + 2 < kN) row_off[base + 2] = excl;
  excl += d2;
  if (base + 3 < kN) row_off[base + 3] = excl;
}

extern "C" __global__ void k_scan2(int* __restrict__ partials, int* __restrict__ row_off) {
  if (threadIdx.x == 0) {
    int run = 0;
    for (int i = 0; i < kScanBlocks; ++i) {
      int v = partials[i];
      partials[i] = run;
      run += v;
    }
    row_off[kN] = run;
  }
}

extern "C" __global__ void k_scan3(int* __restrict__ row_off,
                                   const int* __restrict__ partials,
                                   int* __restrict__ cursor) {
  int i = blockIdx.x * 256 + threadIdx.x;
  if (i < kN) {
    int v = row_off[i] + partials[i >> 10];
    row_off[i] = v;
    cursor[i] = v;
  }
}

extern "C" __global__ void k_scatter(const int* __restrict__ src,
                                     const int* __restrict__ dst,
                                     int* __restrict__ cursor,
                                     int* __restrict__ sorted_src) {
  int e = blockIdx.x * 256 + threadIdx.x;
  if (e < kE) {
    int d = dst[e];
    if ((unsigned)d < (unsigned)kN) {
      int pos = atomicAdd(&cursor[d], 1);
      if ((unsigned)pos < (unsigned)kE) sorted_src[pos] = src[e];
    }
  }
}

// --- fused node update: gather-sum, msg = agg@W_msg, GRU gate/cand ----------
extern "C" __global__ __launch_bounds__(256) void k_node(
    const void* __restrict__ state,
    const void* __restrict__ W_msg,
    const void* __restrict__ W_gate,
    const void* __restrict__ b_gate,
    const void* __restrict__ W_cand,
    const void* __restrict__ b_cand,
    const int* __restrict__ row_off,
    const int* __restrict__ sorted_src,
    const int* __restrict__ flags,
    const float* __restrict__ projected,
    const int* __restrict__ flag,
    void* __restrict__ out) {
  __shared__ float wmf[64 * 64];    // 16 KB
  __shared__ float wgf[128 * 64];   // 32 KB
  __shared__ float wcf[128 * 64];   // 32 KB
  int f32 = flag[0];
  int t = threadIdx.x;
  for (int idx = t; idx < 64 * 64; idx += 256) wmf[idx] = ldf(W_msg, idx, f32);
  for (int idx = t; idx < 128 * 64; idx += 256) {
    wgf[idx] = ldf(W_gate, idx, f32);
    wcf[idx] = ldf(W_cand, idx, f32);
  }
  __syncthreads();

  int wave = t >> 6, lane = t & 63;
  float bg  = ldf(b_gate, lane, f32), bc = ldf(b_cand, lane, f32);
  float pj0 = projected[lane], pj1 = projected[64 + lane];

  for (int i = 0; i < 8; ++i) {
    int n = blockIdx.x * 32 + i * 4 + wave;
    if (n >= kN) continue;
    int ro0 = row_off[n], ro1 = row_off[n + 1];
    ro0 = max(0, min(ro0, kE));          // defensive: finite-wrong beats NaN
    ro1 = max(ro0, min(ro1, kE));

    float a0 = 0.f, a1 = 0.f;
    for (int e = ro0; e < ro1; ++e) {
      int s0 = sorted_src[e];
      if ((unsigned)s0 >= (unsigned)kN) s0 = 0;  // defensive
      a0 += ldf(state, s0 * 64 + lane, f32);
      a1 += ldf(state, kNH + s0 * 64 + lane, f32);
    }
    float sv0 = ldf(state, n * 64 + lane, f32);
    float sv1 = ldf(state, kNH + n * 64 + lane, f32);

    // msg = agg @ W_msg
    float m0 = 0.f, m1 = 0.f;
#pragma unroll
    for (int k2 = 0; k2 < 32; ++k2) {
      float w0 = wmf[(2 * k2) * 64 + lane], w1 = wmf[(2 * k2 + 1) * 64 + lane];
      m0 += __shfl(a0, 2 * k2) * w0 + __shfl(a0, 2 * k2 + 1) * w1;
      m1 += __shfl(a1, 2 * k2) * w0 + __shfl(a1, 2 * k2 + 1) * w1;
    }
    int fl = flags[n];
    float c0 = m0 + (fl ? pj0 : 0.f);
    float c1 = m1 + (fl ? pj1 : 0.f);

    // z = sigmoid([s,c]@W_gate+b), cand = tanh([s,c]@W_cand+b)
    float z0 = bg, z1 = bg, q0 = bc, q1 = bc;
#pragma unroll
    for (int k2 = 0; k2 < 32; ++k2) {
      float g0 = wgf[(2 * k2) * 64 + lane], g1 = wgf[(2 * k2 + 1) * 64 + lane];
      float h0 = wcf[(2 * k2) * 64 + lane], h1 = wcf[(2 * k2 + 1) * 64 + lane];
      float x0 = __shfl(sv0, 2 * k2), x1 = __shfl(sv0, 2 * k2 + 1);
      float y0 = __shfl(sv1, 2 * k2), y1 = __shfl(sv1, 2 * k2 + 1);
      z0 += x0 * g0 + x1 * g1; q0 += x0 * h0 + x1 * h1;
      z1 += y0 * g0 + y1 * g1; q1 += y0 * h0 + y1 * h1;
    }
#pragma unroll
    for (int k2 = 0; k2 < 32; ++k2) {
      float g0 = wgf[(64 + 2 * k2) * 64 + lane], g1 = wgf[(64 + 2 * k2 + 1) * 64 + lane];
      float h0 = wcf[(64 + 2 * k2) * 64 + lane], h1 = wcf[(64 + 2 * k2 + 1) * 64 + lane];
      float x0 = __shfl(c0, 2 * k2), x1 = __shfl(c0, 2 * k2 + 1);
      float y0 = __shfl(c1, 2 * k2), y1 = __shfl(c1, 2 * k2 + 1);
      z0 += x0 * g0 + x1 * g1; q0 += x0 * h0 + x1 * h1;
      z1 += y0 * g0 + y1 * g1; q1 += y0 * h0 + y1 * h1;
    }
    float zz0 = 1.f / (1.f + expf(-z0));
    float zz1 = 1.f / (1.f + expf(-z1));
    float cd0 = tanhf(q0), cd1 = tanhf(q1);
    float ns0 = (1.f - zz0) * sv0 + zz0 * cd0;
    float ns1 = (1.f - zz1) * sv1 + zz1 * cd1;
    stf(out, kOutOff + n * 64 + lane, ns0, f32);
    stf(out, kOutOff + kNH + n * 64 + lane, ns1, f32);
  }
}

// --- readout: mean-pool efferent, tanh decode, policy heads -----------------
extern "C" __global__ void k_readout(const void* __restrict__ W_dec,
                                     const void* __restrict__ b_dec,
                                     const void* __restrict__ W_mean,
                                     const void* __restrict__ b_mean,
                                     const void* __restrict__ W_ls,
                                     const void* __restrict__ b_ls,
                                     const int* __restrict__ eff_idx,
                                     const int* __restrict__ flag,
                                     void* __restrict__ out) {
  __shared__ float ro[128], dec[128];
  int f32 = flag[0];
  int t = threadIdx.x;
  int b = t >> 6, h = t & 63;
  float acc = 0.f;
  for (int i = 0; i < kEff; ++i) {
    int n = eff_idx[i];
    acc += ldf(out, kOutOff + b * kNH + n * 64 + h, f32);
  }
  ro[t] = acc * (1.f / kEff);
  __syncthreads();
  float d = ldf(b_dec, h, f32);
  for (int k = 0; k < 64; ++k) d += ro[b * 64 + k] * ldf(W_dec, k * 64 + h, f32);
  dec[t] = tanhf(d);
  __syncthreads();
  if (t < kB * kA) {
    int bb = t / kA, a = t % kA;
    float m = ldf(b_mean, a, f32), l = ldf(b_ls, a, f32);
    for (int k = 0; k < 64; ++k) {
      float dv = dec[bb * 64 + k];
      m += dv * ldf(W_mean, k * kA + a, f32);
      l += dv * ldf(W_ls, k * kA + a, f32);
    }
    l = fminf(fmaxf(l, -5.f), 2.f);
    stf(out, t, m, f32);            // mean[2][18]
    stf(out, kB * kA + t, l, f32);  // log_std[2][18]
  }
}

extern "C" void kernel_launch(void* const* d_in, const int* in_sizes, int n_in,
                              void* d_out, int out_size, void* d_ws, size_t ws_size,
                              hipStream_t stream) {
  (void)in_sizes; (void)n_in; (void)out_size; (void)ws_size;
  const void* obs    = d_in[0];
  const void* state  = d_in[1];
  const void* W_in   = d_in[2];
  const void* b_in   = d_in[3];
  const void* W_msg  = d_in[4];
  const void* W_gate = d_in[5];
  const void* b_gate = d_in[6];
  const void* W_cand = d_in[7];
  const void* b_cand = d_in[8];
  const void* W_dec  = d_in[9];
  const void* b_dec  = d_in[10];
  const void* W_mean = d_in[11];
  const void* b_mean = d_in[12];
  const void* W_ls   = d_in[13];
  const void* b_ls   = d_in[14];
  const int* src = (const int*)d_in[15];
  const int* dst = (const int*)d_in[16];
  const int* aff = (const int*)d_in[17];
  const int* eff = (const int*)d_in[18];

  // workspace layout (~4.8 MB)
  int* wsp        = (int*)d_ws;
  int* deg        = wsp;                 // [N]
  int* flags      = deg + kN;            // [N]
  int* row_off    = flags + kN;          // [N+1]
  int* cursor     = row_off + (kN + 1);  // [N]
  int* partials   = cursor + kN;         // [64]
  int* dflag      = partials + 64;       // [16]
  float* projected = (float*)(dflag + 16);     // [128]
  int* sorted_src  = (int*)(projected + 128);  // [E]

  hipMemsetAsync(deg, 0, size_t(2) * kN * sizeof(int), stream);  // deg + flags
  k_detect<<<1, 64, 0, stream>>>((const unsigned short*)W_cand, dflag);
  k_prep<<<1, 512, 0, stream>>>(obs, W_in, b_in, aff, dflag, flags, projected);
  k_hist<<<(kE + 255) / 256, 256, 0, stream>>>(dst, deg);
  k_scan1<<<kScanBlocks, 256, 0, stream>>>(deg, row_off, partials);
  k_scan2<<<1, 64, 0, stream>>>(partials, row_off);
  k_scan3<<<(kN + 255) / 256, 256, 0, stream>>>(row_off, partials, cursor);
  k_scatter<<<(kE + 255) / 256, 256, 0, stream>>>(src, dst, cursor, sorted_src);
  k_node<<<(kN + 31) / 32, 256, 0, stream>>>(state, W_msg, W_gate, b_gate, W_cand, b_cand,
                                             row_off, sorted_src, flags, projected, dflag, d_out);
  k_readout<<<1, 128, 0, stream>>>(W_dec, b_dec, W_mean, b_mean, W_ls, b_ls, eff, dflag, d_out);
}

// Round 3
// 1226.425 us; speedup vs baseline: 1.3076x; 1.3076x over previous
//
#include <hip/hip_runtime.h>
#include <hip/hip_bf16.h>

// Problem constants (WholeBrainRateModel)
constexpr int kN   = 50000;    // nodes
constexpr int kH   = 64;       // hidden
constexpr int kB   = 2;        // batch
constexpr int kE   = 1000000;  // edges
constexpr int kObs = 128;
constexpr int kA   = 18;
constexpr int kAff = 512;
constexpr int kEff = 256;
constexpr int kNH  = kN * kH;
constexpr int kOutOff = 2 * kB * kA;  // 72 elements: mean+log_std before next_state
constexpr int kScanChunk  = 1024;
constexpr int kScanBlocks = (kN + kScanChunk - 1) / kScanChunk;  // 49
constexpr int kHistBlocks = (kE + 1023) / 1024;  // 977 (4 edges/thread, 256 thr)

// dtype-adaptive load/store (flag==1 -> float32 buffers, else bf16).
// Used only in prep/pack/epilogue paths, never in the hot gather/GEMV loops.
__device__ __forceinline__ float ldf(const void* p, int i, int f32) {
  if (f32) return ((const float*)p)[i];
  unsigned short u = ((const unsigned short*)p)[i];
  union { unsigned int x; float f; } v; v.x = ((unsigned int)u) << 16; return v.f;
}
__device__ __forceinline__ void stf(void* p, int i, float val, int f32) {
  if (f32) ((float*)p)[i] = val;
  else ((__hip_bfloat16*)p)[i] = __float2bfloat16(val);
}
__device__ __forceinline__ float lo16(unsigned int w) {
  union { unsigned int i; float f; } v; v.i = w << 16; return v.f;
}
__device__ __forceinline__ float hi16(unsigned int w) {
  union { unsigned int i; float f; } v; v.i = w & 0xffff0000u; return v.f;
}
__device__ __forceinline__ unsigned int f2b(float f) {  // rne bf16 bits
  union { float f; unsigned int u; } v; v.f = f;
  unsigned int r = v.u + 0x7fffu + ((v.u >> 16) & 1u);
  return r >> 16;
}

// --- fused: block0 = dtype-detect + afferent flags + obs@W_in; rest = hist --
extern "C" __global__ void k_front(const unsigned short* __restrict__ wprobe,
                                   const void* __restrict__ obs,
                                   const void* __restrict__ W_in,
                                   const void* __restrict__ b_in,
                                   const int* __restrict__ aff_idx,
                                   const int* __restrict__ dst,
                                   int* __restrict__ dflag,
                                   int* __restrict__ flags,
                                   float* __restrict__ projected,
                                   int* __restrict__ deg) {
  int t = threadIdx.x;
  if (blockIdx.x == 0) {
    __shared__ int sflag;
    if (t < 64) {  // dtype detector: sample even u16s of random-normal weights
      int hits = 0;
      for (int k = 0; k < 4; ++k) {
        unsigned short u = wprobe[(t * 4 + k) * 2];
        int e = (u >> 7) & 0xFF;
        if ((u & 0x7FFFu) != 0 && e >= 108 && e <= 128) hits++;
      }
      for (int off = 32; off; off >>= 1) hits += __shfl_down(hits, off);
      if (t == 0) { sflag = (hits < 128) ? 1 : 0; dflag[0] = sflag; }
    }
    __syncthreads();
    int f32 = sflag;
    for (int j = t; j < kAff; j += 256) flags[aff_idx[j]] = 1;
    if (t < kB * kH) {
      int b = t >> 6, h = t & 63;
      float acc = ldf(b_in, h, f32);
      for (int o = 0; o < kObs; ++o)
        acc += ldf(obs, b * kObs + o, f32) * ldf(W_in, o * kH + h, f32);
      projected[t] = acc;
    }
  } else {
    int base = (blockIdx.x - 1) * 1024 + t;
#pragma unroll
    for (int k = 0; k < 4; ++k) {
      int e = base + k * 256;
      if (e < kE) atomicAdd(&deg[dst[e]], 1);
    }
  }
}

// --- pack state: uint(n,h) = bf16(batch0)|bf16(batch1)<<16 ------------------
extern "C" __global__ void k_pack(const void* __restrict__ state,
                                  const int* __restrict__ dflag,
                                  unsigned int* __restrict__ pack) {
  int f32 = dflag[0];
  int i = blockIdx.x * 256 + threadIdx.x;
  if (i < kNH) {
    float v0 = ldf(state, i, f32);
    float v1 = ldf(state, kNH + i, f32);
    pack[i] = f2b(v0) | (f2b(v1) << 16);
  }
}

// --- CSR scan + scatter -----------------------------------------------------
extern "C" __global__ void k_scan1(const int* __restrict__ deg,
                                   int* __restrict__ row_off,
                                   int* __restrict__ partials) {
  __shared__ int sd[256];
  int t = threadIdx.x;
  int base = blockIdx.x * kScanChunk + t * 4;
  int d0 = (base + 0 < kN) ? deg[base + 0] : 0;
  int d1 = (base + 1 < kN) ? deg[base + 1] : 0;
  int d2 = (base + 2 < kN) ? deg[base + 2] : 0;
  int d3 = (base + 3 < kN) ? deg[base + 3] : 0;
  int s4 = d0 + d1 + d2 + d3;
  sd[t] = s4;
  __syncthreads();
  for (int off = 1; off < 256; off <<= 1) {
    int v = (t >= off) ? sd[t - off] : 0;
    __syncthreads();
    sd[t] += v;
    __syncthreads();
  }
  int excl = sd[t] - s4;
  if (t == 255) partials[blockIdx.x] = sd[255];
  if (base + 0 < kN) row_off[base + 0] = excl;
  excl += d0;
  if (base + 1 < kN) row_off[base + 1] = excl;
  excl += d1;
  if (base + 2 < kN) row_off[base + 2] = excl;
  excl += d2;
  if (base + 3 < kN) row_off[base + 3] = excl;
}

extern "C" __global__ void k_scan2(int* __restrict__ partials, int* __restrict__ row_off) {
  if (threadIdx.x == 0) {
    int run = 0;
    for (int i = 0; i < kScanBlocks; ++i) {
      int v = partials[i];
      partials[i] = run;
      run += v;
    }
    row_off[kN] = run;
  }
}

extern "C" __global__ void k_scan3(int* __restrict__ row_off,
                                   const int* __restrict__ partials,
                                   int* __restrict__ cursor) {
  int i = blockIdx.x * 256 + threadIdx.x;
  if (i < kN) {
    int v = row_off[i] + partials[i >> 10];
    row_off[i] = v;
    cursor[i] = v;
  }
}

extern "C" __global__ void k_scatter(const int* __restrict__ src,
                                     const int* __restrict__ dst,
                                     int* __restrict__ cursor,
                                     int* __restrict__ sorted_src) {
  int base = blockIdx.x * 1024 + threadIdx.x;
#pragma unroll
  for (int k = 0; k < 4; ++k) {
    int e = base + k * 256;
    if (e < kE) {
      int pos = atomicAdd(&cursor[dst[e]], 1);
      sorted_src[pos] = src[e];
    }
  }
}

// --- fused node update: gather-sum, msg = agg@W_msg, GRU gate/cand ----------
extern "C" __global__ __launch_bounds__(256) void k_node(
    const void* __restrict__ state,
    const void* __restrict__ W_msg,
    const void* __restrict__ W_gate,
    const void* __restrict__ b_gate,
    const void* __restrict__ W_cand,
    const void* __restrict__ b_cand,
    const unsigned int* __restrict__ pack,
    const int* __restrict__ row_off,
    const int* __restrict__ sorted_src,
    const int* __restrict__ flags,
    const float* __restrict__ projected,
    const int* __restrict__ dflag,
    void* __restrict__ out) {
  __shared__ float wmf[64 * 64];    // 16 KB
  __shared__ float wgf[128 * 64];   // 32 KB
  __shared__ float wcf[128 * 64];   // 32 KB
  int f32 = dflag[0];
  int t = threadIdx.x;
  for (int idx = t; idx < 64 * 64; idx += 256) wmf[idx] = ldf(W_msg, idx, f32);
  for (int idx = t; idx < 128 * 64; idx += 256) {
    wgf[idx] = ldf(W_gate, idx, f32);
    wcf[idx] = ldf(W_cand, idx, f32);
  }
  __syncthreads();

  int wave = t >> 6, lane = t & 63;
  float bg  = ldf(b_gate, lane, f32), bc = ldf(b_cand, lane, f32);
  float pj0 = projected[lane], pj1 = projected[64 + lane];

  for (int i = 0; i < 8; ++i) {
    int n = blockIdx.x * 32 + wave * 8 + i;
    if (n >= kN) continue;
    int ro0 = row_off[n], ro1 = row_off[n + 1];

    // gather-sum of packed bf16 state rows (both batches), 8 loads in flight
    float a0 = 0.f, a1 = 0.f;
    int e = ro0;
    for (; e + 8 <= ro1; e += 8) {
      int s[8];
#pragma unroll
      for (int j = 0; j < 8; ++j) s[j] = sorted_src[e + j];
      unsigned int w[8];
#pragma unroll
      for (int j = 0; j < 8; ++j) w[j] = pack[s[j] * 64 + lane];
#pragma unroll
      for (int j = 0; j < 8; ++j) { a0 += lo16(w[j]); a1 += hi16(w[j]); }
    }
    if (e + 4 <= ro1) {
      int s[4];
#pragma unroll
      for (int j = 0; j < 4; ++j) s[j] = sorted_src[e + j];
      unsigned int w[4];
#pragma unroll
      for (int j = 0; j < 4; ++j) w[j] = pack[s[j] * 64 + lane];
#pragma unroll
      for (int j = 0; j < 4; ++j) { a0 += lo16(w[j]); a1 += hi16(w[j]); }
      e += 4;
    }
    for (; e < ro1; ++e) {
      unsigned int w = pack[sorted_src[e] * 64 + lane];
      a0 += lo16(w); a1 += hi16(w);
    }
    float sv0 = ldf(state, n * 64 + lane, f32);        // full-precision self state
    float sv1 = ldf(state, kNH + n * 64 + lane, f32);

    // msg = agg @ W_msg
    float m0 = 0.f, m1 = 0.f;
#pragma unroll
    for (int k2 = 0; k2 < 32; ++k2) {
      float w0 = wmf[(2 * k2) * 64 + lane], w1 = wmf[(2 * k2 + 1) * 64 + lane];
      m0 += __shfl(a0, 2 * k2) * w0 + __shfl(a0, 2 * k2 + 1) * w1;
      m1 += __shfl(a1, 2 * k2) * w0 + __shfl(a1, 2 * k2 + 1) * w1;
    }
    int fl = flags[n];
    float c0 = m0 + (fl ? pj0 : 0.f);
    float c1 = m1 + (fl ? pj1 : 0.f);

    // z = sigmoid([s,c]@W_gate+b), cand = tanh([s,c]@W_cand+b)
    float z0 = bg, z1 = bg, q0 = bc, q1 = bc;
#pragma unroll
    for (int k2 = 0; k2 < 32; ++k2) {
      float g0 = wgf[(2 * k2) * 64 + lane], g1 = wgf[(2 * k2 + 1) * 64 + lane];
      float h0 = wcf[(2 * k2) * 64 + lane], h1 = wcf[(2 * k2 + 1) * 64 + lane];
      float x0 = __shfl(sv0, 2 * k2), x1 = __shfl(sv0, 2 * k2 + 1);
      float y0 = __shfl(sv1, 2 * k2), y1 = __shfl(sv1, 2 * k2 + 1);
      z0 += x0 * g0 + x1 * g1; q0 += x0 * h0 + x1 * h1;
      z1 += y0 * g0 + y1 * g1; q1 += y0 * h0 + y1 * h1;
    }
#pragma unroll
    for (int k2 = 0; k2 < 32; ++k2) {
      float g0 = wgf[(64 + 2 * k2) * 64 + lane], g1 = wgf[(64 + 2 * k2 + 1) * 64 + lane];
      float h0 = wcf[(64 + 2 * k2) * 64 + lane], h1 = wcf[(64 + 2 * k2 + 1) * 64 + lane];
      float x0 = __shfl(c0, 2 * k2), x1 = __shfl(c0, 2 * k2 + 1);
      float y0 = __shfl(c1, 2 * k2), y1 = __shfl(c1, 2 * k2 + 1);
      z0 += x0 * g0 + x1 * g1; q0 += x0 * h0 + x1 * h1;
      z1 += y0 * g0 + y1 * g1; q1 += y0 * h0 + y1 * h1;
    }
    float zz0 = 1.f / (1.f + __expf(-z0));
    float zz1 = 1.f / (1.f + __expf(-z1));
    float cd0 = tanhf(q0), cd1 = tanhf(q1);
    float ns0 = (1.f - zz0) * sv0 + zz0 * cd0;
    float ns1 = (1.f - zz1) * sv1 + zz1 * cd1;
    stf(out, kOutOff + n * 64 + lane, ns0, f32);
    stf(out, kOutOff + kNH + n * 64 + lane, ns1, f32);
  }
}

// --- readout: mean-pool efferent, tanh decode, policy heads -----------------
extern "C" __global__ void k_readout(const void* __restrict__ W_dec,
                                     const void* __restrict__ b_dec,
                                     const void* __restrict__ W_mean,
                                     const void* __restrict__ b_mean,
                                     const void* __restrict__ W_ls,
                                     const void* __restrict__ b_ls,
                                     const int* __restrict__ eff_idx,
                                     const int* __restrict__ dflag,
                                     void* __restrict__ out) {
  __shared__ float part[8][64];
  __shared__ float ro[128], dec[128];
  int f32 = dflag[0];
  int t = threadIdx.x;          // 512 threads = 8 waves
  int wv = t >> 6, lane = t & 63;
  int b = wv >> 2, g = wv & 3;  // wave -> (batch, quarter of eff list)
  float acc = 0.f;
#pragma unroll 4
  for (int i = 0; i < 64; ++i) {
    int n = eff_idx[g * 64 + i];
    acc += ldf(out, kOutOff + b * kNH + n * 64 + lane, f32);
  }
  part[wv][lane] = acc;
  __syncthreads();
  if (t < 128) {
    int bb = t >> 6, h = t & 63;
    float s = part[bb * 4 + 0][h] + part[bb * 4 + 1][h] +
              part[bb * 4 + 2][h] + part[bb * 4 + 3][h];
    ro[t] = s * (1.f / kEff);
  }
  __syncthreads();
  if (t < 128) {
    int bb = t >> 6, h = t & 63;
    float d = ldf(b_dec, h, f32);
    for (int k = 0; k < 64; ++k) d += ro[bb * 64 + k] * ldf(W_dec, k * 64 + h, f32);
    dec[t] = tanhf(d);
  }
  __syncthreads();
  if (t < kB * kA) {
    int bb = t / kA, a = t % kA;
    float m = ldf(b_mean, a, f32), l = ldf(b_ls, a, f32);
    for (int k = 0; k < 64; ++k) {
      float dv = dec[bb * 64 + k];
      m += dv * ldf(W_mean, k * kA + a, f32);
      l += dv * ldf(W_ls, k * kA + a, f32);
    }
    l = fminf(fmaxf(l, -5.f), 2.f);
    stf(out, t, m, f32);            // mean[2][18]
    stf(out, kB * kA + t, l, f32);  // log_std[2][18]
  }
}

extern "C" void kernel_launch(void* const* d_in, const int* in_sizes, int n_in,
                              void* d_out, int out_size, void* d_ws, size_t ws_size,
                              hipStream_t stream) {
  (void)in_sizes; (void)n_in; (void)out_size; (void)ws_size;
  const void* obs    = d_in[0];
  const void* state  = d_in[1];
  const void* W_in   = d_in[2];
  const void* b_in   = d_in[3];
  const void* W_msg  = d_in[4];
  const void* W_gate = d_in[5];
  const void* b_gate = d_in[6];
  const void* W_cand = d_in[7];
  const void* b_cand = d_in[8];
  const void* W_dec  = d_in[9];
  const void* b_dec  = d_in[10];
  const void* W_mean = d_in[11];
  const void* b_mean = d_in[12];
  const void* W_ls   = d_in[13];
  const void* b_ls   = d_in[14];
  const int* src = (const int*)d_in[15];
  const int* dst = (const int*)d_in[16];
  const int* aff = (const int*)d_in[17];
  const int* eff = (const int*)d_in[18];

  // workspace layout (~17.8 MB)
  int* wsp        = (int*)d_ws;
  int* deg        = wsp;                 // [N]
  int* flags      = deg + kN;            // [N]
  int* row_off    = flags + kN;          // [N+1]
  int* cursor     = row_off + (kN + 1);  // [N]
  int* partials   = cursor + kN;         // [64]
  int* dflag      = partials + 64;       // [16]
  float* projected = (float*)(dflag + 16);        // [128]
  int* sorted_src  = (int*)(projected + 128);     // [E]
  unsigned int* pk = (unsigned int*)(sorted_src + kE);  // [N*H]

  hipMemsetAsync(deg, 0, size_t(2) * kN * sizeof(int), stream);  // deg + flags
  k_front<<<1 + kHistBlocks, 256, 0, stream>>>(
      (const unsigned short*)W_cand, obs, W_in, b_in, aff, dst,
      dflag, flags, projected, deg);
  k_pack<<<(kNH + 255) / 256, 256, 0, stream>>>(state, dflag, pk);
  k_scan1<<<kScanBlocks, 256, 0, stream>>>(deg, row_off, partials);
  k_scan2<<<1, 64, 0, stream>>>(partials, row_off);
  k_scan3<<<(kN + 255) / 256, 256, 0, stream>>>(row_off, partials, cursor);
  k_scatter<<<kHistBlocks, 256, 0, stream>>>(src, dst, cursor, sorted_src);
  k_node<<<(kN + 31) / 32, 256, 0, stream>>>(state, W_msg, W_gate, b_gate, W_cand, b_cand,
                                             pk, row_off, sorted_src, flags, projected,
                                             dflag, d_out);
  k_readout<<<1, 512, 0, stream>>>(W_dec, b_dec, W_mean, b_mean, W_ls, b_ls, eff,
                                   dflag, d_out);
}

// Round 4
// 869.921 us; speedup vs baseline: 1.8434x; 1.4098x over previous
//
#include <hip/hip_runtime.h>
#include <hip/hip_bf16.h>

// Problem constants (WholeBrainRateModel)
constexpr int kN   = 50000;    // nodes
constexpr int kH   = 64;       // hidden
constexpr int kB   = 2;        // batch
constexpr int kE   = 1000000;  // edges
constexpr int kObs = 128;
constexpr int kA   = 18;
constexpr int kAff = 512;
constexpr int kEff = 256;
constexpr int kNH  = kN * kH;
constexpr int kOutOff = 2 * kB * kA;  // 72 elements: mean+log_std before next_state
constexpr int kScanChunk  = 1024;
constexpr int kScanBlocks = (kN + kScanChunk - 1) / kScanChunk;  // 49
constexpr int kHistBlocks = (kE + 1023) / 1024;  // 977 (4 edges/thread, 256 thr)

// dtype-adaptive load/store (flag==1 -> float32 buffers, else bf16).
// Only on cold paths (prep/pack/weight-stage/epilogue), never in hot loops.
__device__ __forceinline__ float ldf(const void* p, int i, int f32) {
  if (f32) return ((const float*)p)[i];
  unsigned short u = ((const unsigned short*)p)[i];
  union { unsigned int x; float f; } v; v.x = ((unsigned int)u) << 16; return v.f;
}
__device__ __forceinline__ void stf(void* p, int i, float val, int f32) {
  if (f32) ((float*)p)[i] = val;
  else ((__hip_bfloat16*)p)[i] = __float2bfloat16(val);
}
__device__ __forceinline__ float lo16(unsigned int w) {
  union { unsigned int i; float f; } v; v.i = w << 16; return v.f;
}
__device__ __forceinline__ float hi16(unsigned int w) {
  union { unsigned int i; float f; } v; v.i = w & 0xffff0000u; return v.f;
}
__device__ __forceinline__ unsigned int f2b(float f) {  // rne bf16 bits
  union { float f; unsigned int u; } v; v.f = f;
  unsigned int r = v.u + 0x7fffu + ((v.u >> 16) & 1u);
  return r >> 16;
}

// --- fused: block0 = dtype-detect + afferent flags + obs@W_in; rest = hist --
extern "C" __global__ void k_front(const unsigned short* __restrict__ wprobe,
                                   const void* __restrict__ obs,
                                   const void* __restrict__ W_in,
                                   const void* __restrict__ b_in,
                                   const int* __restrict__ aff_idx,
                                   const int* __restrict__ dst,
                                   int* __restrict__ dflag,
                                   int* __restrict__ flags,
                                   float* __restrict__ projected,
                                   int* __restrict__ deg) {
  int t = threadIdx.x;
  if (blockIdx.x == 0) {
    __shared__ int sflag;
    if (t < 64) {  // dtype detector: sample even u16s of random-normal weights
      int hits = 0;
      for (int k = 0; k < 4; ++k) {
        unsigned short u = wprobe[(t * 4 + k) * 2];
        int e = (u >> 7) & 0xFF;
        if ((u & 0x7FFFu) != 0 && e >= 108 && e <= 128) hits++;
      }
      for (int off = 32; off; off >>= 1) hits += __shfl_down(hits, off);
      if (t == 0) { sflag = (hits < 128) ? 1 : 0; dflag[0] = sflag; }
    }
    __syncthreads();
    int f32 = sflag;
    for (int j = t; j < kAff; j += 256) flags[aff_idx[j]] = 1;
    if (t < kB * kH) {
      int b = t >> 6, h = t & 63;
      float acc = ldf(b_in, h, f32);
      for (int o = 0; o < kObs; ++o)
        acc += ldf(obs, b * kObs + o, f32) * ldf(W_in, o * kH + h, f32);
      projected[t] = acc;
    }
  } else {
    int base = (blockIdx.x - 1) * 1024 + t;
#pragma unroll
    for (int k = 0; k < 4; ++k) {
      int e = base + k * 256;
      if (e < kE) atomicAdd(&deg[dst[e]], 1);
    }
  }
}

// --- pack state: uint(n,h) = bf16(batch0)|bf16(batch1)<<16 ------------------
extern "C" __global__ void k_pack(const void* __restrict__ state,
                                  const int* __restrict__ dflag,
                                  unsigned int* __restrict__ pack) {
  int f32 = dflag[0];
  int i = blockIdx.x * 256 + threadIdx.x;
  if (i < kNH) {
    float v0 = ldf(state, i, f32);
    float v1 = ldf(state, kNH + i, f32);
    pack[i] = f2b(v0) | (f2b(v1) << 16);
  }
}

// --- CSR scan + scatter -----------------------------------------------------
extern "C" __global__ void k_scan1(const int* __restrict__ deg,
                                   int* __restrict__ row_off,
                                   int* __restrict__ partials) {
  __shared__ int sd[256];
  int t = threadIdx.x;
  int base = blockIdx.x * kScanChunk + t * 4;
  int d0 = (base + 0 < kN) ? deg[base + 0] : 0;
  int d1 = (base + 1 < kN) ? deg[base + 1] : 0;
  int d2 = (base + 2 < kN) ? deg[base + 2] : 0;
  int d3 = (base + 3 < kN) ? deg[base + 3] : 0;
  int s4 = d0 + d1 + d2 + d3;
  sd[t] = s4;
  __syncthreads();
  for (int off = 1; off < 256; off <<= 1) {
    int v = (t >= off) ? sd[t - off] : 0;
    __syncthreads();
    sd[t] += v;
    __syncthreads();
  }
  int excl = sd[t] - s4;
  if (t == 255) partials[blockIdx.x] = sd[255];
  if (base + 0 < kN) row_off[base + 0] = excl;
  excl += d0;
  if (base + 1 < kN) row_off[base + 1] = excl;
  excl += d1;
  if (base + 2 < kN) row_off[base + 2] = excl;
  excl += d2;
  if (base + 3 < kN) row_off[base + 3] = excl;
}

extern "C" __global__ void k_scan2(int* __restrict__ partials, int* __restrict__ row_off) {
  if (threadIdx.x == 0) {
    int run = 0;
    for (int i = 0; i < kScanBlocks; ++i) {
      int v = partials[i];
      partials[i] = run;
      run += v;
    }
    row_off[kN] = run;
  }
}

extern "C" __global__ void k_scan3(int* __restrict__ row_off,
                                   const int* __restrict__ partials,
                                   int* __restrict__ cursor) {
  int i = blockIdx.x * 256 + threadIdx.x;
  if (i < kN) {
    int v = row_off[i] + partials[i >> 10];
    row_off[i] = v;
    cursor[i] = v;
  }
}

extern "C" __global__ void k_scatter(const int* __restrict__ src,
                                     const int* __restrict__ dst,
                                     int* __restrict__ cursor,
                                     int* __restrict__ sorted_src) {
  int base = blockIdx.x * 1024 + threadIdx.x;
#pragma unroll
  for (int k = 0; k < 4; ++k) {
    int e = base + k * 256;
    if (e < kE) {
      int pos = atomicAdd(&cursor[dst[e]], 1);
      sorted_src[pos] = src[e];
    }
  }
}

// --- gather: one wave per node, agg = sum of packed neighbor rows -----------
extern "C" __global__ __launch_bounds__(256) void k_gather(
    const unsigned int* __restrict__ pack,
    const int* __restrict__ row_off,
    const int* __restrict__ sorted_src,
    unsigned int* __restrict__ agg) {
  int wave = threadIdx.x >> 6, lane = threadIdx.x & 63;
  int n = blockIdx.x * 4 + wave;
  if (n >= kN) return;
  int ro0 = row_off[n], ro1 = row_off[n + 1];
  float a0 = 0.f, a1 = 0.f;
  int e = ro0;
  for (; e + 8 <= ro1; e += 8) {
    int s[8];
#pragma unroll
    for (int j = 0; j < 8; ++j) s[j] = sorted_src[e + j];
    unsigned int w[8];
#pragma unroll
    for (int j = 0; j < 8; ++j) w[j] = pack[s[j] * 64 + lane];
#pragma unroll
    for (int j = 0; j < 8; ++j) { a0 += lo16(w[j]); a1 += hi16(w[j]); }
  }
  if (e + 4 <= ro1) {
    int s[4];
#pragma unroll
    for (int j = 0; j < 4; ++j) s[j] = sorted_src[e + j];
    unsigned int w[4];
#pragma unroll
    for (int j = 0; j < 4; ++j) w[j] = pack[s[j] * 64 + lane];
#pragma unroll
    for (int j = 0; j < 4; ++j) { a0 += lo16(w[j]); a1 += hi16(w[j]); }
    e += 4;
  }
  for (; e < ro1; ++e) {
    unsigned int w = pack[sorted_src[e] * 64 + lane];
    a0 += lo16(w); a1 += hi16(w);
  }
  agg[n * 64 + lane] = f2b(a0) | (f2b(a1) << 16);
}

// --- update: msg = agg@W_msg (+inject), GRU gate/cand, next_state -----------
extern "C" __global__ __launch_bounds__(256) void k_update(
    const void* __restrict__ state,
    const void* __restrict__ W_msg,
    const void* __restrict__ W_gate,
    const void* __restrict__ b_gate,
    const void* __restrict__ W_cand,
    const void* __restrict__ b_cand,
    const unsigned int* __restrict__ agg,
    const int* __restrict__ flags,
    const float* __restrict__ projected,
    const int* __restrict__ dflag,
    void* __restrict__ out) {
  // bf16 row-pair-packed weights: word k2*64+j = (W[2k2][j], W[2k2+1][j])
  __shared__ unsigned int wm[32 * 64];  //  8 KB
  __shared__ unsigned int wg[64 * 64];  // 16 KB
  __shared__ unsigned int wc[64 * 64];  // 16 KB
  int f32 = dflag[0];
  int t = threadIdx.x;
  for (int idx = t; idx < 32 * 64; idx += 256) {
    int k2 = idx >> 6, j = idx & 63;
    wm[idx] = f2b(ldf(W_msg, (2 * k2) * 64 + j, f32)) |
              (f2b(ldf(W_msg, (2 * k2 + 1) * 64 + j, f32)) << 16);
  }
  for (int idx = t; idx < 64 * 64; idx += 256) {
    int k2 = idx >> 6, j = idx & 63;
    wg[idx] = f2b(ldf(W_gate, (2 * k2) * 64 + j, f32)) |
              (f2b(ldf(W_gate, (2 * k2 + 1) * 64 + j, f32)) << 16);
    wc[idx] = f2b(ldf(W_cand, (2 * k2) * 64 + j, f32)) |
              (f2b(ldf(W_cand, (2 * k2 + 1) * 64 + j, f32)) << 16);
  }
  __syncthreads();

  int wave = t >> 6, lane = t & 63;
  float bg  = ldf(b_gate, lane, f32), bc = ldf(b_cand, lane, f32);
  float pj0 = projected[lane], pj1 = projected[64 + lane];

#pragma unroll 1
  for (int i = 0; i < 8; ++i) {
    int n = blockIdx.x * 32 + wave * 8 + i;
    if (n >= kN) continue;
    unsigned int ag = agg[n * 64 + lane];
    float a0 = lo16(ag), a1 = hi16(ag);
    float sv0 = ldf(state, n * 64 + lane, f32);
    float sv1 = ldf(state, kNH + n * 64 + lane, f32);

    // msg = agg @ W_msg
    float m0 = 0.f, m1 = 0.f;
#pragma unroll
    for (int k2 = 0; k2 < 32; ++k2) {
      unsigned int w = wm[k2 * 64 + lane];
      float w0 = lo16(w), w1 = hi16(w);
      m0 += __shfl(a0, 2 * k2) * w0 + __shfl(a0, 2 * k2 + 1) * w1;
      m1 += __shfl(a1, 2 * k2) * w0 + __shfl(a1, 2 * k2 + 1) * w1;
    }
    int fl = flags[n];
    float c0 = m0 + (fl ? pj0 : 0.f);
    float c1 = m1 + (fl ? pj1 : 0.f);

    // z = sigmoid([s,c]@W_gate+b), cand = tanh([s,c]@W_cand+b)
    float z0 = bg, z1 = bg, q0 = bc, q1 = bc;
#pragma unroll
    for (int k2 = 0; k2 < 32; ++k2) {
      unsigned int g = wg[k2 * 64 + lane], c = wc[k2 * 64 + lane];
      float g0 = lo16(g), g1 = hi16(g), h0 = lo16(c), h1 = hi16(c);
      float x0 = __shfl(sv0, 2 * k2), x1 = __shfl(sv0, 2 * k2 + 1);
      float y0 = __shfl(sv1, 2 * k2), y1 = __shfl(sv1, 2 * k2 + 1);
      z0 += x0 * g0 + x1 * g1; q0 += x0 * h0 + x1 * h1;
      z1 += y0 * g0 + y1 * g1; q1 += y0 * h0 + y1 * h1;
    }
#pragma unroll
    for (int k2 = 0; k2 < 32; ++k2) {
      unsigned int g = wg[(32 + k2) * 64 + lane], c = wc[(32 + k2) * 64 + lane];
      float g0 = lo16(g), g1 = hi16(g), h0 = lo16(c), h1 = hi16(c);
      float x0 = __shfl(c0, 2 * k2), x1 = __shfl(c0, 2 * k2 + 1);
      float y0 = __shfl(c1, 2 * k2), y1 = __shfl(c1, 2 * k2 + 1);
      z0 += x0 * g0 + x1 * g1; q0 += x0 * h0 + x1 * h1;
      z1 += y0 * g0 + y1 * g1; q1 += y0 * h0 + y1 * h1;
    }
    float zz0 = 1.f / (1.f + __expf(-z0));
    float zz1 = 1.f / (1.f + __expf(-z1));
    float cd0 = tanhf(q0), cd1 = tanhf(q1);
    float ns0 = (1.f - zz0) * sv0 + zz0 * cd0;
    float ns1 = (1.f - zz1) * sv1 + zz1 * cd1;
    stf(out, kOutOff + n * 64 + lane, ns0, f32);
    stf(out, kOutOff + kNH + n * 64 + lane, ns1, f32);
  }
}

// --- readout: mean-pool efferent, tanh decode, policy heads -----------------
extern "C" __global__ void k_readout(const void* __restrict__ W_dec,
                                     const void* __restrict__ b_dec,
                                     const void* __restrict__ W_mean,
                                     const void* __restrict__ b_mean,
                                     const void* __restrict__ W_ls,
                                     const void* __restrict__ b_ls,
                                     const int* __restrict__ eff_idx,
                                     const int* __restrict__ dflag,
                                     void* __restrict__ out) {
  __shared__ float part[8][64];
  __shared__ float ro[128], dec[128];
  int f32 = dflag[0];
  int t = threadIdx.x;          // 512 threads = 8 waves
  int wv = t >> 6, lane = t & 63;
  int b = wv >> 2, g = wv & 3;  // wave -> (batch, quarter of eff list)
  float acc = 0.f;
#pragma unroll 4
  for (int i = 0; i < 64; ++i) {
    int n = eff_idx[g * 64 + i];
    acc += ldf(out, kOutOff + b * kNH + n * 64 + lane, f32);
  }
  part[wv][lane] = acc;
  __syncthreads();
  if (t < 128) {
    int bb = t >> 6, h = t & 63;
    float s = part[bb * 4 + 0][h] + part[bb * 4 + 1][h] +
              part[bb * 4 + 2][h] + part[bb * 4 + 3][h];
    ro[t] = s * (1.f / kEff);
  }
  __syncthreads();
  if (t < 128) {
    int bb = t >> 6, h = t & 63;
    float d = ldf(b_dec, h, f32);
    for (int k = 0; k < 64; ++k) d += ro[bb * 64 + k] * ldf(W_dec, k * 64 + h, f32);
    dec[t] = tanhf(d);
  }
  __syncthreads();
  if (t < kB * kA) {
    int bb = t / kA, a = t % kA;
    float m = ldf(b_mean, a, f32), l = ldf(b_ls, a, f32);
    for (int k = 0; k < 64; ++k) {
      float dv = dec[bb * 64 + k];
      m += dv * ldf(W_mean, k * kA + a, f32);
      l += dv * ldf(W_ls, k * kA + a, f32);
    }
    l = fminf(fmaxf(l, -5.f), 2.f);
    stf(out, t, m, f32);            // mean[2][18]
    stf(out, kB * kA + t, l, f32);  // log_std[2][18]
  }
}

extern "C" void kernel_launch(void* const* d_in, const int* in_sizes, int n_in,
                              void* d_out, int out_size, void* d_ws, size_t ws_size,
                              hipStream_t stream) {
  (void)in_sizes; (void)n_in; (void)out_size; (void)ws_size;
  const void* obs    = d_in[0];
  const void* state  = d_in[1];
  const void* W_in   = d_in[2];
  const void* b_in   = d_in[3];
  const void* W_msg  = d_in[4];
  const void* W_gate = d_in[5];
  const void* b_gate = d_in[6];
  const void* W_cand = d_in[7];
  const void* b_cand = d_in[8];
  const void* W_dec  = d_in[9];
  const void* b_dec  = d_in[10];
  const void* W_mean = d_in[11];
  const void* b_mean = d_in[12];
  const void* W_ls   = d_in[13];
  const void* b_ls   = d_in[14];
  const int* src = (const int*)d_in[15];
  const int* dst = (const int*)d_in[16];
  const int* aff = (const int*)d_in[17];
  const int* eff = (const int*)d_in[18];

  // workspace layout (~31 MB)
  int* wsp        = (int*)d_ws;
  int* deg        = wsp;                 // [N]
  int* flags      = deg + kN;            // [N]
  int* row_off    = flags + kN;          // [N+1]
  int* cursor     = row_off + (kN + 1);  // [N]
  int* partials   = cursor + kN;         // [64]
  int* dflag      = partials + 64;       // [16]
  float* projected = (float*)(dflag + 16);        // [128]
  int* sorted_src  = (int*)(projected + 128);     // [E]
  unsigned int* pk  = (unsigned int*)(sorted_src + kE);  // [N*H]
  unsigned int* agg = pk + kNH;                          // [N*H]

  hipMemsetAsync(deg, 0, size_t(2) * kN * sizeof(int), stream);  // deg + flags
  k_front<<<1 + kHistBlocks, 256, 0, stream>>>(
      (const unsigned short*)W_cand, obs, W_in, b_in, aff, dst,
      dflag, flags, projected, deg);
  k_pack<<<(kNH + 255) / 256, 256, 0, stream>>>(state, dflag, pk);
  k_scan1<<<kScanBlocks, 256, 0, stream>>>(deg, row_off, partials);
  k_scan2<<<1, 64, 0, stream>>>(partials, row_off);
  k_scan3<<<(kN + 255) / 256, 256, 0, stream>>>(row_off, partials, cursor);
  k_scatter<<<kHistBlocks, 256, 0, stream>>>(src, dst, cursor, sorted_src);
  k_gather<<<(kN + 3) / 4, 256, 0, stream>>>(pk, row_off, sorted_src, agg);
  k_update<<<(kN + 31) / 32, 256, 0, stream>>>(state, W_msg, W_gate, b_gate, W_cand, b_cand,
                                               agg, flags, projected, dflag, d_out);
  k_readout<<<1, 512, 0, stream>>>(W_dec, b_dec, W_mean, b_mean, W_ls, b_ls, eff,
                                   dflag, d_out);
}

// Round 5
// 391.575 us; speedup vs baseline: 4.0954x; 2.2216x over previous
//
#include <hip/hip_runtime.h>
#include <hip/hip_bf16.h>

// Problem constants (WholeBrainRateModel)
constexpr int kN   = 50000;    // nodes
constexpr int kH   = 64;       // hidden
constexpr int kB   = 2;        // batch
constexpr int kE   = 1000000;  // edges
constexpr int kObs = 128;
constexpr int kA   = 18;
constexpr int kAff = 512;
constexpr int kEff = 256;
constexpr int kNH  = kN * kH;
constexpr int kOutOff = 2 * kB * kA;  // 72 elements: mean+log_std before next_state
constexpr int kScanChunk  = 1024;
constexpr int kScanBlocks = (kN + kScanChunk - 1) / kScanChunk;  // 49
constexpr int kHistBlocks = (kE + 1023) / 1024;  // 977 (4 edges/thread, 256 thr)

typedef __attribute__((ext_vector_type(8))) short short8_t;  // 8 bf16 (4 VGPRs)
typedef __attribute__((ext_vector_type(4))) float f32x4_t;

// dtype-adaptive load/store (flag==1 -> float32 buffers, else bf16).
__device__ __forceinline__ float ldf(const void* p, int i, int f32) {
  if (f32) return ((const float*)p)[i];
  unsigned short u = ((const unsigned short*)p)[i];
  union { unsigned int x; float f; } v; v.x = ((unsigned int)u) << 16; return v.f;
}
__device__ __forceinline__ void stf(void* p, int i, float val, int f32) {
  if (f32) ((float*)p)[i] = val;
  else ((__hip_bfloat16*)p)[i] = __float2bfloat16(val);
}
__device__ __forceinline__ float lo16(unsigned int w) {
  union { unsigned int i; float f; } v; v.i = w << 16; return v.f;
}
__device__ __forceinline__ float hi16(unsigned int w) {
  union { unsigned int i; float f; } v; v.i = w & 0xffff0000u; return v.f;
}
__device__ __forceinline__ unsigned int f2b(float f) {  // rne bf16 bits
  union { float f; unsigned int u; } v; v.f = f;
  unsigned int r = v.u + 0x7fffu + ((v.u >> 16) & 1u);
  return r >> 16;
}

// --- fused: block0 = dtype-detect + afferent flags + obs@W_in; rest = hist --
extern "C" __global__ void k_front(const unsigned short* __restrict__ wprobe,
                                   const void* __restrict__ obs,
                                   const void* __restrict__ W_in,
                                   const void* __restrict__ b_in,
                                   const int* __restrict__ aff_idx,
                                   const int* __restrict__ dst,
                                   int* __restrict__ dflag,
                                   int* __restrict__ flags,
                                   float* __restrict__ projected,
                                   int* __restrict__ deg) {
  int t = threadIdx.x;
  if (blockIdx.x == 0) {
    __shared__ int sflag;
    if (t < 64) {  // dtype detector: sample even u16s of random-normal weights
      int hits = 0;
      for (int k = 0; k < 4; ++k) {
        unsigned short u = wprobe[(t * 4 + k) * 2];
        int e = (u >> 7) & 0xFF;
        if ((u & 0x7FFFu) != 0 && e >= 108 && e <= 128) hits++;
      }
      for (int off = 32; off; off >>= 1) hits += __shfl_down(hits, off);
      if (t == 0) { sflag = (hits < 128) ? 1 : 0; dflag[0] = sflag; }
    }
    __syncthreads();
    int f32 = sflag;
    for (int j = t; j < kAff; j += 256) flags[aff_idx[j]] = 1;
    if (t < kB * kH) {
      int b = t >> 6, h = t & 63;
      float acc = ldf(b_in, h, f32);
      for (int o = 0; o < kObs; ++o)
        acc += ldf(obs, b * kObs + o, f32) * ldf(W_in, o * kH + h, f32);
      projected[t] = acc;
    }
  } else {
    int base = (blockIdx.x - 1) * 1024 + t;
#pragma unroll
    for (int k = 0; k < 4; ++k) {
      int e = base + k * 256;
      if (e < kE) atomicAdd(&deg[dst[e]], 1);
    }
  }
}

// --- pack state: uint(n,h) = bf16(batch0)|bf16(batch1)<<16 ------------------
extern "C" __global__ void k_pack(const void* __restrict__ state,
                                  const int* __restrict__ dflag,
                                  unsigned int* __restrict__ pack) {
  int f32 = dflag[0];
  int i = blockIdx.x * 256 + threadIdx.x;
  if (i < kNH) {
    float v0 = ldf(state, i, f32);
    float v1 = ldf(state, kNH + i, f32);
    pack[i] = f2b(v0) | (f2b(v1) << 16);
  }
}

// --- weight prep: Wt[n][k] bf16, regions: msg[64x64] gate[64x128] cand[64x128]
extern "C" __global__ void k_wprep(const void* __restrict__ W_msg,
                                   const void* __restrict__ W_gate,
                                   const void* __restrict__ W_cand,
                                   const int* __restrict__ dflag,
                                   unsigned short* __restrict__ wt) {
  int f32 = dflag[0];
  int i = blockIdx.x * 256 + threadIdx.x;  // 0..20479
  if (i < 4096) {
    int n = i >> 6, k = i & 63;
    wt[i] = (unsigned short)f2b(ldf(W_msg, k * 64 + n, f32));
  } else if (i < 12288) {
    int j = i - 4096; int n = j >> 7, k = j & 127;
    wt[i] = (unsigned short)f2b(ldf(W_gate, k * 64 + n, f32));
  } else if (i < 20480) {
    int j = i - 12288; int n = j >> 7, k = j & 127;
    wt[i] = (unsigned short)f2b(ldf(W_cand, k * 64 + n, f32));
  }
}

// --- CSR scan + scatter -----------------------------------------------------
extern "C" __global__ void k_scan1(const int* __restrict__ deg,
                                   int* __restrict__ row_off,
                                   int* __restrict__ partials) {
  __shared__ int sd[256];
  int t = threadIdx.x;
  int base = blockIdx.x * kScanChunk + t * 4;
  int d0 = (base + 0 < kN) ? deg[base + 0] : 0;
  int d1 = (base + 1 < kN) ? deg[base + 1] : 0;
  int d2 = (base + 2 < kN) ? deg[base + 2] : 0;
  int d3 = (base + 3 < kN) ? deg[base + 3] : 0;
  int s4 = d0 + d1 + d2 + d3;
  sd[t] = s4;
  __syncthreads();
  for (int off = 1; off < 256; off <<= 1) {
    int v = (t >= off) ? sd[t - off] : 0;
    __syncthreads();
    sd[t] += v;
    __syncthreads();
  }
  int excl = sd[t] - s4;
  if (t == 255) partials[blockIdx.x] = sd[255];
  if (base + 0 < kN) row_off[base + 0] = excl;
  excl += d0;
  if (base + 1 < kN) row_off[base + 1] = excl;
  excl += d1;
  if (base + 2 < kN) row_off[base + 2] = excl;
  excl += d2;
  if (base + 3 < kN) row_off[base + 3] = excl;
}

extern "C" __global__ void k_scan2(int* __restrict__ partials, int* __restrict__ row_off) {
  if (threadIdx.x == 0) {
    int run = 0;
    for (int i = 0; i < kScanBlocks; ++i) {
      int v = partials[i];
      partials[i] = run;
      run += v;
    }
    row_off[kN] = run;
  }
}

extern "C" __global__ void k_scan3(int* __restrict__ row_off,
                                   const int* __restrict__ partials,
                                   int* __restrict__ cursor) {
  int i = blockIdx.x * 256 + threadIdx.x;
  if (i < kN) {
    int v = row_off[i] + partials[i >> 10];
    row_off[i] = v;
    cursor[i] = v;
  }
}

extern "C" __global__ void k_scatter(const int* __restrict__ src,
                                     const int* __restrict__ dst,
                                     int* __restrict__ cursor,
                                     int* __restrict__ sorted_src) {
  int base = blockIdx.x * 1024 + threadIdx.x;
#pragma unroll
  for (int k = 0; k < 4; ++k) {
    int e = base + k * 256;
    if (e < kE) {
      int pos = atomicAdd(&cursor[dst[e]], 1);
      sorted_src[pos] = src[e];
    }
  }
}

// --- gather: one wave per node, agg = sum of packed neighbor rows -----------
extern "C" __global__ __launch_bounds__(256) void k_gather(
    const unsigned int* __restrict__ pack,
    const int* __restrict__ row_off,
    const int* __restrict__ sorted_src,
    unsigned int* __restrict__ agg) {
  int wave = threadIdx.x >> 6, lane = threadIdx.x & 63;
  int n = blockIdx.x * 4 + wave;
  if (n >= kN) return;
  int ro0 = row_off[n], ro1 = row_off[n + 1];
  float a0 = 0.f, a1 = 0.f;
  int e = ro0;
  for (; e + 8 <= ro1; e += 8) {
    int s[8];
#pragma unroll
    for (int j = 0; j < 8; ++j) s[j] = sorted_src[e + j];
    unsigned int w[8];
#pragma unroll
    for (int j = 0; j < 8; ++j) w[j] = pack[s[j] * 64 + lane];
#pragma unroll
    for (int j = 0; j < 8; ++j) { a0 += lo16(w[j]); a1 += hi16(w[j]); }
  }
  if (e + 4 <= ro1) {
    int s[4];
#pragma unroll
    for (int j = 0; j < 4; ++j) s[j] = sorted_src[e + j];
    unsigned int w[4];
#pragma unroll
    for (int j = 0; j < 4; ++j) w[j] = pack[s[j] * 64 + lane];
#pragma unroll
    for (int j = 0; j < 4; ++j) { a0 += lo16(w[j]); a1 += hi16(w[j]); }
    e += 4;
  }
  for (; e < ro1; ++e) {
    unsigned int w = pack[sorted_src[e] * 64 + lane];
    a0 += lo16(w); a1 += hi16(w);
  }
  agg[n * 64 + lane] = f2b(a0) | (f2b(a1) << 16);
}

// --- update (MFMA): msg = agg@W_msg (+inject), GRU gate/cand, next_state ----
// Block: 32 nodes x 2 batches = 64 M-rows. Wave w owns rows [16w,16w+16).
// X LDS [64][136]: cols 0-63 state bf16, cols 64-127 agg -> combined.
// A-frag: lane holds A[m=lane&15][k=(lane>>4)*8+j]; B-frag: B[k][n=lane&15];
// C: col=lane&15, row=(lane>>4)*4+reg (verified mappings, learn_hip m89/m91).
extern "C" __global__ __launch_bounds__(256) void k_update(
    const void* __restrict__ state,
    const unsigned short* __restrict__ wt,   // prepped bf16 Wt msg|gate|cand
    const void* __restrict__ b_gate,
    const void* __restrict__ b_cand,
    const unsigned int* __restrict__ agg,
    const int* __restrict__ flags,
    const float* __restrict__ projected,
    const int* __restrict__ dflag,
    void* __restrict__ out) {
  __shared__ unsigned short lx[64 * 136];     // 17408 B
  __shared__ unsigned short lwt[22016];       // 44032 B: msg@0(72/row) gate@4608 cand@13312(136/row)
  __shared__ float sbias[128];                // gate 0-63 | cand 64-127
  __shared__ float sproj[128];
  __shared__ int   sfl[32];
  int f32 = dflag[0];
  int t = threadIdx.x;
  int nd0 = blockIdx.x * 32;

  // stage weights (u32 = bf16 pair, k-contiguous)
  const unsigned int* w32 = (const unsigned int*)wt;
  for (int i = t; i < 2048; i += 256) {                 // msg
    int n = i >> 5, k2 = i & 31;
    *(unsigned int*)&lwt[n * 72 + 2 * k2] = w32[i];
  }
  for (int i = t; i < 4096; i += 256) {                 // gate
    int n = i >> 6, k2 = i & 63;
    *(unsigned int*)&lwt[4608 + n * 136 + 2 * k2] = w32[2048 + i];
  }
  for (int i = t; i < 4096; i += 256) {                 // cand
    int n = i >> 6, k2 = i & 63;
    *(unsigned int*)&lwt[13312 + n * 136 + 2 * k2] = w32[6144 + i];
  }
  // stage state bf16 -> X cols 0-63
  for (int i = t; i < 4096; i += 256) {
    int row = i >> 6, col = i & 63;
    int ndg = min(nd0 + (row >> 1), kN - 1), b = row & 1;
    lx[row * 136 + col] = (unsigned short)f2b(ldf(state, b * kNH + ndg * 64 + col, f32));
  }
  // stage agg (packed both batches) -> X cols 64-127
  for (int i = t; i < 2048; i += 256) {
    int ndl = i >> 6, col = i & 63;
    unsigned int ag = agg[min(nd0 + ndl, kN - 1) * 64 + col];
    lx[(2 * ndl) * 136 + 64 + col]     = (unsigned short)(ag & 0xffffu);
    lx[(2 * ndl + 1) * 136 + 64 + col] = (unsigned short)(ag >> 16);
  }
  if (t < 64) sbias[t] = ldf(b_gate, t, f32);
  else if (t < 128) sbias[t] = ldf(b_cand, t - 64, f32);
  else sproj[t - 128] = projected[t - 128];
  if (t < 32) sfl[t] = (nd0 + t < kN) ? flags[nd0 + t] : 0;
  __syncthreads();

  int w = t >> 6, lane = t & 63;
  int q = lane >> 4, l15 = lane & 15;
  int rowb = w * 16;

  // --- msg phase: C[16x64] = agg[16x64] @ W_msg[64x64] ---
  short8_t a0 = *(const short8_t*)&lx[(rowb + l15) * 136 + 64 + q * 8];
  short8_t a1 = *(const short8_t*)&lx[(rowb + l15) * 136 + 96 + q * 8];
  f32x4_t msgc[4];
#pragma unroll
  for (int ct = 0; ct < 4; ++ct) {
    f32x4_t acc = {0.f, 0.f, 0.f, 0.f};
    short8_t b0 = *(const short8_t*)&lwt[(ct * 16 + l15) * 72 + q * 8];
    short8_t b1 = *(const short8_t*)&lwt[(ct * 16 + l15) * 72 + 32 + q * 8];
    acc = __builtin_amdgcn_mfma_f32_16x16x32_bf16(a0, b0, acc, 0, 0, 0);
    acc = __builtin_amdgcn_mfma_f32_16x16x32_bf16(a1, b1, acc, 0, 0, 0);
    msgc[ct] = acc;
  }
  // combined = msg + inject -> back into X cols 64-127 (own strip rows only)
#pragma unroll
  for (int ct = 0; ct < 4; ++ct) {
    int col = ct * 16 + l15;
    float pj0 = sproj[col], pj1 = sproj[64 + col];
#pragma unroll
    for (int r = 0; r < 4; ++r) {
      int row = rowb + q * 4 + r;
      int ndl = row >> 1, b = row & 1;
      float inj = sfl[ndl] ? (b ? pj1 : pj0) : 0.f;
      lx[row * 136 + 64 + col] = (unsigned short)f2b(msgc[ct][r] + inj);
    }
  }

  // --- gate/cand phase: K=128 over [state | combined] ---
  short8_t xa[4];
#pragma unroll
  for (int ks = 0; ks < 4; ++ks)
    xa[ks] = *(const short8_t*)&lx[(rowb + l15) * 136 + ks * 32 + q * 8];
#pragma unroll
  for (int ct = 0; ct < 4; ++ct) {
    f32x4_t accg = {0.f, 0.f, 0.f, 0.f}, accc = {0.f, 0.f, 0.f, 0.f};
#pragma unroll
    for (int ks = 0; ks < 4; ++ks) {
      short8_t bg = *(const short8_t*)&lwt[4608 + (ct * 16 + l15) * 136 + ks * 32 + q * 8];
      short8_t bc = *(const short8_t*)&lwt[13312 + (ct * 16 + l15) * 136 + ks * 32 + q * 8];
      accg = __builtin_amdgcn_mfma_f32_16x16x32_bf16(xa[ks], bg, accg, 0, 0, 0);
      accc = __builtin_amdgcn_mfma_f32_16x16x32_bf16(xa[ks], bc, accc, 0, 0, 0);
    }
    int col = ct * 16 + l15;
    float bgv = sbias[col], bcv = sbias[64 + col];
#pragma unroll
    for (int r = 0; r < 4; ++r) {
      int row = rowb + q * 4 + r;
      int nd = nd0 + (row >> 1), b = row & 1;
      if (nd >= kN) continue;
      float z  = 1.f / (1.f + __expf(-(accg[r] + bgv)));
      float cd = tanhf(accc[r] + bcv);
      float sv = ldf(state, b * kNH + nd * 64 + col, f32);
      float ns = (1.f - z) * sv + z * cd;
      stf(out, kOutOff + b * kNH + nd * 64 + col, ns, f32);
    }
  }
}

// --- readout: mean-pool efferent, tanh decode, policy heads -----------------
extern "C" __global__ void k_readout(const void* __restrict__ W_dec,
                                     const void* __restrict__ b_dec,
                                     const void* __restrict__ W_mean,
                                     const void* __restrict__ b_mean,
                                     const void* __restrict__ W_ls,
                                     const void* __restrict__ b_ls,
                                     const int* __restrict__ eff_idx,
                                     const int* __restrict__ dflag,
                                     void* __restrict__ out) {
  __shared__ float part[8][64];
  __shared__ float ro[128], dec[128];
  int f32 = dflag[0];
  int t = threadIdx.x;          // 512 threads = 8 waves
  int wv = t >> 6, lane = t & 63;
  int b = wv >> 2, g = wv & 3;  // wave -> (batch, quarter of eff list)
  float acc = 0.f;
#pragma unroll 4
  for (int i = 0; i < 64; ++i) {
    int n = eff_idx[g * 64 + i];
    acc += ldf(out, kOutOff + b * kNH + n * 64 + lane, f32);
  }
  part[wv][lane] = acc;
  __syncthreads();
  if (t < 128) {
    int bb = t >> 6, h = t & 63;
    float s = part[bb * 4 + 0][h] + part[bb * 4 + 1][h] +
              part[bb * 4 + 2][h] + part[bb * 4 + 3][h];
    ro[t] = s * (1.f / kEff);
  }
  __syncthreads();
  if (t < 128) {
    int bb = t >> 6, h = t & 63;
    float d = ldf(b_dec, h, f32);
    for (int k = 0; k < 64; ++k) d += ro[bb * 64 + k] * ldf(W_dec, k * 64 + h, f32);
    dec[t] = tanhf(d);
  }
  __syncthreads();
  if (t < kB * kA) {
    int bb = t / kA, a = t % kA;
    float m = ldf(b_mean, a, f32), l = ldf(b_ls, a, f32);
    for (int k = 0; k < 64; ++k) {
      float dv = dec[bb * 64 + k];
      m += dv * ldf(W_mean, k * kA + a, f32);
      l += dv * ldf(W_ls, k * kA + a, f32);
    }
    l = fminf(fmaxf(l, -5.f), 2.f);
    stf(out, t, m, f32);            // mean[2][18]
    stf(out, kB * kA + t, l, f32);  // log_std[2][18]
  }
}

extern "C" void kernel_launch(void* const* d_in, const int* in_sizes, int n_in,
                              void* d_out, int out_size, void* d_ws, size_t ws_size,
                              hipStream_t stream) {
  (void)in_sizes; (void)n_in; (void)out_size; (void)ws_size;
  const void* obs    = d_in[0];
  const void* state  = d_in[1];
  const void* W_in   = d_in[2];
  const void* b_in   = d_in[3];
  const void* W_msg  = d_in[4];
  const void* W_gate = d_in[5];
  const void* b_gate = d_in[6];
  const void* W_cand = d_in[7];
  const void* b_cand = d_in[8];
  const void* W_dec  = d_in[9];
  const void* b_dec  = d_in[10];
  const void* W_mean = d_in[11];
  const void* b_mean = d_in[12];
  const void* W_ls   = d_in[13];
  const void* b_ls   = d_in[14];
  const int* src = (const int*)d_in[15];
  const int* dst = (const int*)d_in[16];
  const int* aff = (const int*)d_in[17];
  const int* eff = (const int*)d_in[18];

  // workspace layout (~31 MB)
  int* wsp        = (int*)d_ws;
  int* deg        = wsp;                 // [N]
  int* flags      = deg + kN;            // [N]
  int* row_off    = flags + kN;          // [N+1]
  int* cursor     = row_off + (kN + 1);  // [N]
  int* partials   = cursor + kN;         // [64]
  int* dflag      = partials + 64;       // [16]
  float* projected = (float*)(dflag + 16);        // [128]
  int* sorted_src  = (int*)(projected + 128);     // [E]
  unsigned int* pk  = (unsigned int*)(sorted_src + kE);  // [N*H]
  unsigned int* agg = pk + kNH;                          // [N*H]
  unsigned short* wt = (unsigned short*)(agg + kNH);     // [20480] bf16

  hipMemsetAsync(deg, 0, size_t(2) * kN * sizeof(int), stream);  // deg + flags
  k_front<<<1 + kHistBlocks, 256, 0, stream>>>(
      (const unsigned short*)W_cand, obs, W_in, b_in, aff, dst,
      dflag, flags, projected, deg);
  k_pack<<<(kNH + 255) / 256, 256, 0, stream>>>(state, dflag, pk);
  k_wprep<<<80, 256, 0, stream>>>(W_msg, W_gate, W_cand, dflag, wt);
  k_scan1<<<kScanBlocks, 256, 0, stream>>>(deg, row_off, partials);
  k_scan2<<<1, 64, 0, stream>>>(partials, row_off);
  k_scan3<<<(kN + 255) / 256, 256, 0, stream>>>(row_off, partials, cursor);
  k_scatter<<<kHistBlocks, 256, 0, stream>>>(src, dst, cursor, sorted_src);
  k_gather<<<(kN + 3) / 4, 256, 0, stream>>>(pk, row_off, sorted_src, agg);
  k_update<<<(kN + 31) / 32, 256, 0, stream>>>(state, wt, b_gate, b_cand,
                                               agg, flags, projected, dflag, d_out);
  k_readout<<<1, 512, 0, stream>>>(W_dec, b_dec, W_mean, b_mean, W_ls, b_ls, eff,
                                   dflag, d_out);
}